// Round 16
// baseline (68.846 us; speedup 1.0000x reference)
//
#include <hip/hip_runtime.h>
#include <hip/hip_bf16.h>

// Sparse self-attention == dense attention within each residue class (mod 4)
// + 7-wide window (duplicate entries => logit += 1.0 in log2 space)
// + OOB window slots adding exp2(0)=1 to the denominator
// + zero key n=1024 folded into the epilogue denominator.
// prep (W transpose ONLY) -> fused QKV GEMM (A staged as fp32 directly from x
// via async global_load_lds, converted at consume; XCD-chunked grid) ->
// flash attn (R13: triple-buffered K/V, one barrier per tile).

#define BATCH 2
#define LSEQ  4096
#define DMODEL 512
#define NH    8
#define DHEAD 64
#define NPAD  1088      // K/V row stride (valid rows 0..1023; tails never touched)
#define QSCALE 0.18033688011112042f   // 0.125 * log2(e)

typedef __bf16 bf16x8 __attribute__((ext_vector_type(8)));
typedef __attribute__((ext_vector_type(4))) float f32x4;
typedef unsigned short u16;
typedef unsigned int u32;
typedef __attribute__((ext_vector_type(8))) u16 u16x8;
typedef __attribute__((ext_vector_type(4))) u16 u16x4;
typedef __attribute__((ext_vector_type(4))) u32 u32x4;

__device__ __forceinline__ u16 f2bf(float f) {
    u32 u = __float_as_uint(f);
    u += 0x7fffu + ((u >> 16) & 1u);   // RNE, finite inputs
    return (u16)(u >> 16);
}

__device__ __forceinline__ u16 cvt_bf(float f) {
    __bf16 t = (__bf16)f;              // native v_cvt on gfx950
    return *(const u16*)&t;
}

__device__ __forceinline__ u32 cvtpk(float lo, float hi) {
    u32 d;
    asm("v_cvt_pk_bf16_f32 %0, %1, %2" : "=v"(d) : "v"(lo), "v"(hi));
    return d;
}

__device__ __forceinline__ void gload16(const void* g, void* l) {
    __builtin_amdgcn_global_load_lds(
        (const __attribute__((address_space(1))) u32*)g,
        (__attribute__((address_space(3))) u32*)l, 16, 0, 0);
}

// ---------------------------------------------------------------------------
// prep: Wt[c][k] = bf16(W_mat[k][col]) transposed; c = mat*512 + col.
// 192 blocks, one 64x64 tile each.
// ---------------------------------------------------------------------------
__global__ __launch_bounds__(256) void prep_kernel(
    const float* __restrict__ Wq, const float* __restrict__ Wk, const float* __restrict__ Wv,
    u16* __restrict__ Wt)
{
    const int wb  = blockIdx.x;            // 0..191
    const int tid = threadIdx.x;
    const int mat = wb >> 6;
    const int t   = wb & 63;
    const int k0  = (t >> 3) * 64, c0 = (t & 7) * 64;
    const float* W = (mat == 0) ? Wq : (mat == 1) ? Wk : Wv;
    __shared__ u16 Ws[64][72];             // [k][c]
    #pragma unroll
    for (int i = 0; i < 4; ++i) {
        const int chunk = i * 256 + tid;
        const int kr = chunk >> 4, c4 = (chunk & 15) * 4;
        float4 v = *(const float4*)(W + (size_t)(k0 + kr) * DMODEL + c0 + c4);
        u16x4 q = { f2bf(v.x), f2bf(v.y), f2bf(v.z), f2bf(v.w) };
        *(u16x4*)&Ws[kr][c4] = q;
    }
    __syncthreads();
    const int cc = tid >> 2, kq = (tid & 3) * 16;
    alignas(16) u16 tmp[16];
    #pragma unroll
    for (int kk = 0; kk < 16; ++kk) tmp[kk] = Ws[kq + kk][cc];
    u16* dst = Wt + (size_t)(mat * 512 + c0 + cc) * DMODEL + k0 + kq;
    *(u16x8*)dst       = *(const u16x8*)&tmp[0];
    *(u16x8*)(dst + 8) = *(const u16x8*)&tmp[8];
}

// ---------------------------------------------------------------------------
// Fused QKV GEMM: C = x(8192x512 fp32) * Wt^T(512x1536), BM=BN=128, BK=64,
// 4 waves. A staged fp32 via global_load_lds (swizzled half-chunks), cvt at
// consume. B staged bf16 via global_load_lds. 1-D grid, XCD-chunked.
// nt 0-3 -> Q (scaled), 4-7 -> K, 8-11 -> V (written transposed via LDS).
// ---------------------------------------------------------------------------
__global__ __launch_bounds__(256) void gemm_kernel(
    const float* __restrict__ x, const u16* __restrict__ Wt,
    u16* __restrict__ Qb, u16* __restrict__ Kb, u16* __restrict__ Vb)
{
    const int bid = blockIdx.x;
    const int xcd = bid & 7;
    const int j   = bid >> 3;            // 0..95
    const int mt  = xcd * 8 + (j / 12);  // 0..63
    const int nt  = j % 12;
    const int m0 = mt * 128;
    const int n0 = nt * 128;
    const int tid = threadIdx.x;
    const int w = tid >> 6, l = tid & 63, lr = l & 15, lh = l >> 4;
    const int wr = w >> 1, wc = w & 1;

    // A: 128x64 fp32 (32 KB) | B: 128x64 bf16 (16 KB) = 48 KB; V-retile aliases A.
    __shared__ __align__(16) u32 smem32[12288];
    float* As32 = (float*)smem32;                 // 8192 floats
    u16*   Bs   = (u16*)(smem32 + 8192);          // 8192 u16
    u16*   Vr   = (u16*)smem32;                   // V-retile 128*132 u16 (33 KB)

    f32x4 acc[4][4];
    const f32x4 fzero = {0.f, 0.f, 0.f, 0.f};
    #pragma unroll
    for (int mi = 0; mi < 4; ++mi)
        #pragma unroll
        for (int nj = 0; nj < 4; ++nj) acc[mi][nj] = fzero;

    for (int kt = 0; kt < 8; ++kt) {
        const int k0 = kt * 64;
        // B: 4 gload_lds (bf16, chunk-swizzled)
        #pragma unroll
        for (int i = 0; i < 4; ++i) {
            const int cid = i * 256 + tid;
            const int row = cid >> 3, ch = cid & 7;
            const int sch = ch ^ (row & 7);
            gload16(Wt + (size_t)(n0 + row) * DMODEL + k0 + sch * 8,
                    Bs + (i * 256 + w * 64) * 8);
        }
        // A: 8 gload_lds (fp32 half-chunks of 4 floats, swizzled preserving
        // 32B chunk contiguity: hc ^ ((row&7)<<1))
        #pragma unroll
        for (int i = 0; i < 8; ++i) {
            const int cid = i * 256 + tid;        // 0..2047
            const int row = cid >> 4, hc = cid & 15;
            const int shc = hc ^ ((row & 7) << 1);
            gload16(x + (size_t)(m0 + row) * DMODEL + k0 + shc * 4,
                    As32 + (size_t)(i * 256 + w * 64) * 4);
        }
        __syncthreads();

        #pragma unroll
        for (int kk = 0; kk < 2; ++kk) {
            const int cs = (kk * 4 + lh) ^ (lr & 7);   // swizzled 8-elem chunk
            bf16x8 af[4], bfr[4];
            #pragma unroll
            for (int mi = 0; mi < 4; ++mi) {
                const float* ap = As32 + ((size_t)(wr * 64 + mi * 16 + lr) * 64 + cs * 8);
                float4 a0 = *(const float4*)ap;
                float4 a1 = *(const float4*)(ap + 4);
                u32x4 av = { cvtpk(a0.x, a0.y), cvtpk(a0.z, a0.w),
                             cvtpk(a1.x, a1.y), cvtpk(a1.z, a1.w) };
                af[mi] = __builtin_bit_cast(bf16x8, av);
            }
            #pragma unroll
            for (int nj = 0; nj < 4; ++nj)
                bfr[nj] = *(const bf16x8*)(Bs + (wc * 64 + nj * 16 + lr) * 64 + cs * 8);
            #pragma unroll
            for (int mi = 0; mi < 4; ++mi)
                #pragma unroll
                for (int nj = 0; nj < 4; ++nj)
                    acc[mi][nj] = __builtin_amdgcn_mfma_f32_16x16x32_bf16(af[mi], bfr[nj], acc[mi][nj], 0, 0, 0);
        }
        __syncthreads();
    }

    const int mat = nt >> 2;
    const int hp  = nt & 3;
    if (mat < 2) {
        u16* Ob = (mat == 0) ? Qb : Kb;
        const float osc = (mat == 0) ? QSCALE : 1.0f;
        #pragma unroll
        for (int mi = 0; mi < 4; ++mi) {
            const int gmb = m0 + wr * 64 + mi * 16 + lh * 4;
            const int b = gmb >> 12;
            #pragma unroll
            for (int rr = 0; rr < 4; ++rr) {
                const int t = (gmb + rr) & 4095;
                const int n = t >> 2, r = t & 3;
                #pragma unroll
                for (int nj = 0; nj < 4; ++nj) {
                    const int c  = wc * 64 + nj * 16 + lr;
                    const int h  = hp * 2 + (c >> 6);
                    const int dk = c & 63;
                    const size_t g = ((size_t)(b * NH + h)) * 4 + r;
                    Ob[(g * NPAD + n) * DHEAD + dk] = f2bf(acc[mi][nj][rr] * osc);
                }
            }
        }
    } else {
        // V: retile via LDS -> coalesced stores of V^T [g][dv][n]
        #pragma unroll
        for (int mi = 0; mi < 4; ++mi) {
            const int nrel = wr * 16 + mi * 4 + lh;
            #pragma unroll
            for (int nj = 0; nj < 4; ++nj) {
                const int c = wc * 64 + nj * 16 + lr;
                #pragma unroll
                for (int rr = 0; rr < 4; ++rr)
                    Vr[c * 132 + rr * 32 + nrel] = f2bf(acc[mi][nj][rr]);
            }
        }
        __syncthreads();
        const int b  = m0 >> 12;
        const int nb = (m0 & 4095) >> 2;
        #pragma unroll
        for (int e = 0; e < 2; ++e) {
            const int chunk = e * 256 + tid;
            const int c = chunk & 127, r = chunk >> 7;
            const int h  = hp * 2 + (c >> 6);
            const int dv = c & 63;
            const size_t g = ((size_t)(b * NH + h)) * 4 + r;
            u16* dst = Vb + (g * DHEAD + dv) * NPAD + nb;
            const u16* src = Vr + c * 132 + r * 32;
            alignas(16) u16 tmp[32];
            #pragma unroll
            for (int q8 = 0; q8 < 8; ++q8)
                *(u16x4*)&tmp[q8 * 4] = *(const u16x4*)(src + q8 * 4);
            #pragma unroll
            for (int q16 = 0; q16 < 4; ++q16)
                *(u16x8*)(dst + q16 * 8) = *(const u16x8*)&tmp[q16 * 8];
        }
    }
}

// ---------------------------------------------------------------------------
// Flash attention per (b,h,r): 128 queries/block (8 waves x 16 rows),
// 16 key tiles of 64. Triple-buffered K/V, ONE barrier per tile.  [R13]
// ---------------------------------------------------------------------------
__global__ __launch_bounds__(512) void attn_kernel(
    const u16* __restrict__ Qb, const u16* __restrict__ Kb, const u16* __restrict__ Vb,
    float* __restrict__ out)
{
    const int g  = blockIdx.x;          // ((b*8+h)*4+r): blocks sharing g -> same XCD
    const int b  = g >> 5;
    const int h  = (g >> 2) & 7;
    const int r  = g & 3;
    const int q0 = blockIdx.y * 128;
    const int tid = threadIdx.x;
    const int w  = tid >> 6;            // 0..7
    const int l  = tid & 63;
    const int lr = l & 15, lh = l >> 4;

    const u16* Qg  = Qb + (size_t)g * NPAD * DHEAD;
    const u16* Kg  = Kb + (size_t)g * NPAD * DHEAD;
    const u16* Vtg = Vb + (size_t)g * DHEAD * NPAD;   // [dv][n]

    __shared__ u16 KV[3][2][4096];   // [buf][K/V][64 rows][8 slots][8 u16]
    __shared__ u16 Ps[8][16][68];    // per-wave P tile [qrow][m]

    // staging: thread -> (row = tid>>3, slot = tid&7), source chunk XOR-swizzled
    const int srow = tid >> 3;
    const int ssch = (tid & 7) ^ (srow & 7);
    const u16* ksrc0 = Kg  + (size_t)srow * DHEAD + ssch * 8;
    const u16* vsrc0 = Vtg + (size_t)srow * NPAD  + ssch * 8;

    bf16x8 qa[2];
    {
        const u16* qrow = Qg + (size_t)(q0 + w * 16 + lr) * DHEAD;
        qa[0] = *(const bf16x8*)(qrow + lh * 8);
        qa[1] = *(const bf16x8*)(qrow + 32 + lh * 8);
    }

    const f32x4 fzero = {0.f, 0.f, 0.f, 0.f};
    f32x4 o[4];
    #pragma unroll
    for (int j = 0; j < 4; ++j) o[j] = fzero;
    float Lpart[4] = {0.f, 0.f, 0.f, 0.f};

    const int qw0 = q0 + w * 16;

    // prologue: stage tiles 0,1 into bufs 0,1
    gload16(ksrc0,              &KV[0][0][w * 512]);
    gload16(vsrc0,              &KV[0][1][w * 512]);
    gload16(ksrc0 + 64 * DHEAD, &KV[1][0][w * 512]);
    gload16(vsrc0 + 64,         &KV[1][1][w * 512]);

    for (int mt = 0; mt < 16; ++mt) {
        if (mt < 15) asm volatile("s_waitcnt vmcnt(2)" ::: "memory");
        else         asm volatile("s_waitcnt vmcnt(0)" ::: "memory");
        __builtin_amdgcn_s_barrier();
        // issue tile mt+2 AFTER the barrier (WAR-safe vs readers of tile mt-1)
        if (mt < 14) {
            const int nb = (mt + 2) % 3;
            gload16(ksrc0 + (size_t)(mt + 2) * 64 * DHEAD, &KV[nb][0][w * 512]);
            gload16(vsrc0 + (mt + 2) * 64,                 &KV[nb][1][w * 512]);
        }

        const u16* Kbuf = KV[mt % 3][0];
        const u16* Vbuf = KV[mt % 3][1];

        // S = Q K^T (wave: 16 x 64), logits already in log2 space
        f32x4 s[4];
        __builtin_amdgcn_s_setprio(1);
        #pragma unroll
        for (int ni = 0; ni < 4; ++ni) {
            const int rbase = (ni * 16 + lr) * 8;
            const int sl0 = lh ^ (lr & 7), sl1 = (4 + lh) ^ (lr & 7);
            bf16x8 kb0 = *(const bf16x8*)(Kbuf + (rbase + sl0) * 8);
            bf16x8 kb1 = *(const bf16x8*)(Kbuf + (rbase + sl1) * 8);
            f32x4 t = __builtin_amdgcn_mfma_f32_16x16x32_bf16(qa[0], kb0, fzero, 0, 0, 0);
            s[ni] = __builtin_amdgcn_mfma_f32_16x16x32_bf16(qa[1], kb1, t, 0, 0, 0);
        }
        __builtin_amdgcn_s_setprio(0);

        const int m0 = mt * 64;
        const bool special = (m0 + 66 >= qw0) && (m0 <= qw0 + 18);
        if (!special) {
            #pragma unroll
            for (int ni = 0; ni < 4; ++ni) {
                #pragma unroll
                for (int rr = 0; rr < 4; ++rr) {
                    const float p = __builtin_amdgcn_exp2f(s[ni][rr]);
                    Lpart[rr] += p;
                    Ps[w][lh * 4 + rr][ni * 16 + lr] = cvt_bf(p);
                }
            }
        } else {
            #pragma unroll
            for (int ni = 0; ni < 4; ++ni) {
                const int mg = m0 + ni * 16 + lr;
                #pragma unroll
                for (int rr = 0; rr < 4; ++rr) {
                    const int qg = qw0 + lh * 4 + rr;
                    float v = s[ni][rr];
                    const int dd = mg - qg;
                    if (dd >= -3 && dd <= 3) v += 1.0f;    // window doubling
                    const float p = __builtin_amdgcn_exp2f(v);
                    Lpart[rr] += p;
                    Ps[w][lh * 4 + rr][ni * 16 + lr] = cvt_bf(p);
                }
            }
        }

        // O += P V (Ps per-wave: intra-wave lgkmcnt ordering only)
        __builtin_amdgcn_s_setprio(1);
        #pragma unroll
        for (int kk = 0; kk < 2; ++kk) {
            const int slot = (kk * 4 + lh) ^ (lr & 7);
            bf16x8 pa = *(const bf16x8*)&Ps[w][lr][kk * 32 + lh * 8];
            #pragma unroll
            for (int j = 0; j < 4; ++j) {
                bf16x8 vb = *(const bf16x8*)(Vbuf + ((j * 16 + lr) * 8 + slot) * 8);
                o[j] = __builtin_amdgcn_mfma_f32_16x16x32_bf16(pa, vb, o[j], 0, 0, 0);
            }
        }
        __builtin_amdgcn_s_setprio(0);
        // no trailing barrier: next iteration's barrier covers the WAR hazard
    }

    // epilogue: dense zero-key (+1), its window double (q>=1021 ? +1), OOB (+coob)
    #pragma unroll
    for (int rr = 0; rr < 4; ++rr) {
        float s_ = Lpart[rr];
        #pragma unroll
        for (int off = 1; off < 16; off <<= 1)
            s_ += __shfl_xor(s_, off, 16);
        const int qg = qw0 + lh * 4 + rr;
        const int coob = (qg < 3 ? 3 - qg : 0) + (qg > 1021 ? qg - 1021 : 0);
        const float extra = (float)(coob + 1 + (qg >= 1021 ? 1 : 0));
        const float inv = 1.0f / (s_ + extra);
        const int t = qg * 4 + r;
        float* orow = out + ((size_t)b * LSEQ + t) * DMODEL + h * DHEAD;
        #pragma unroll
        for (int j = 0; j < 4; ++j)
            orow[j * 16 + lr] = o[j][rr] * inv;
    }
}

extern "C" void kernel_launch(void* const* d_in, const int* in_sizes, int n_in,
                              void* d_out, int out_size, void* d_ws, size_t ws_size,
                              hipStream_t stream) {
    const float* x  = (const float*)d_in[0];
    const float* Wq = (const float*)d_in[1];
    const float* Wk = (const float*)d_in[2];
    const float* Wv = (const float*)d_in[3];
    float* out = (float*)d_out;

    const size_t SZ = (size_t)BATCH * NH * 4 * NPAD * DHEAD;   // per-tensor elems
    u16* Qb = (u16*)d_ws;
    u16* Kb = Qb + SZ;
    u16* Vb = Kb + SZ;

    // transposed-W scratch lives in d_out (fully overwritten by attn later)
    u16* Wt = (u16*)d_out;                       // 1536*512 u16 = 1.5 MB

    prep_kernel<<<192, 256, 0, stream>>>(Wq, Wk, Wv, Wt);

    gemm_kernel<<<768, 256, 0, stream>>>(x, Wt, Qb, Kb, Vb);

    dim3 ga(64, 8);
    attn_kernel<<<ga, 512, 0, stream>>>(Qb, Kb, Vb, out);
}

// Round 17
// 65.321 us; speedup vs baseline: 1.0540x; 1.0540x over previous
//
#include <hip/hip_runtime.h>
#include <hip/hip_bf16.h>

// Sparse self-attention == dense attention within each residue class (mod 4)
// + 7-wide window (duplicate entries => logit += 1.0 in log2 space)
// + OOB window slots adding exp2(0)=1 to the denominator
// + zero key n=1024 folded into the epilogue denominator.
// prep (x->bf16, W transpose) -> fused QKV GEMM (XCD-chunked) -> flash attn
// (triple-buffered K/V staging with ONE barrier per tile).  [R13 best: 65.41us]

#define BATCH 2
#define LSEQ  4096
#define DMODEL 512
#define NH    8
#define DHEAD 64
#define NPAD  1088      // K/V row stride (valid rows 0..1023; tails never touched)
#define QSCALE 0.18033688011112042f   // 0.125 * log2(e)

typedef __bf16 bf16x8 __attribute__((ext_vector_type(8)));
typedef __attribute__((ext_vector_type(4))) float f32x4;
typedef unsigned short u16;
typedef unsigned int u32;
typedef __attribute__((ext_vector_type(8))) u16 u16x8;
typedef __attribute__((ext_vector_type(4))) u16 u16x4;

__device__ __forceinline__ u16 f2bf(float f) {
    u32 u = __float_as_uint(f);
    u += 0x7fffu + ((u >> 16) & 1u);   // RNE, finite inputs
    return (u16)(u >> 16);
}

__device__ __forceinline__ u16 cvt_bf(float f) {
    __bf16 t = (__bf16)f;              // native v_cvt on gfx950
    return *(const u16*)&t;
}

__device__ __forceinline__ void gload16(const u16* g, u16* l) {
    __builtin_amdgcn_global_load_lds(
        (const __attribute__((address_space(1))) u32*)(const void*)g,
        (__attribute__((address_space(3))) u32*)(void*)l, 16, 0, 0);
}

// ---------------------------------------------------------------------------
// prep: bid<2048: xb = bf16(x);  2048..2239: Wt[c][k] = bf16(W[k][c]) transposed
// ---------------------------------------------------------------------------
__global__ __launch_bounds__(256) void prep_kernel(
    const float* __restrict__ x,
    const float* __restrict__ Wq, const float* __restrict__ Wk, const float* __restrict__ Wv,
    u16* __restrict__ xb, u16* __restrict__ Wt)
{
    const int bid = blockIdx.x, tid = threadIdx.x;
    if (bid < 2048) {
        const size_t i0 = (size_t)bid * 2048 + (size_t)tid * 8;
        float4 a = *(const float4*)(x + i0);
        float4 b = *(const float4*)(x + i0 + 4);
        u16x8 o = { f2bf(a.x), f2bf(a.y), f2bf(a.z), f2bf(a.w),
                    f2bf(b.x), f2bf(b.y), f2bf(b.z), f2bf(b.w) };
        *(u16x8*)(xb + i0) = o;
    } else {
        const int wb  = bid - 2048;            // 0..191
        const int mat = wb >> 6;
        const int t   = wb & 63;
        const int k0  = (t >> 3) * 64, c0 = (t & 7) * 64;
        const float* W = (mat == 0) ? Wq : (mat == 1) ? Wk : Wv;
        __shared__ u16 Ws[64][72];             // [k][c]
        #pragma unroll
        for (int i = 0; i < 4; ++i) {
            const int chunk = i * 256 + tid;
            const int kr = chunk >> 4, c4 = (chunk & 15) * 4;
            float4 v = *(const float4*)(W + (size_t)(k0 + kr) * DMODEL + c0 + c4);
            u16x4 q = { f2bf(v.x), f2bf(v.y), f2bf(v.z), f2bf(v.w) };
            *(u16x4*)&Ws[kr][c4] = q;
        }
        __syncthreads();
        const int cc = tid >> 2, kq = (tid & 3) * 16;
        alignas(16) u16 tmp[16];
        #pragma unroll
        for (int kk = 0; kk < 16; ++kk) tmp[kk] = Ws[kq + kk][cc];
        u16* dst = Wt + (size_t)(mat * 512 + c0 + cc) * DMODEL + k0 + kq;
        *(u16x8*)dst       = *(const u16x8*)&tmp[0];
        *(u16x8*)(dst + 8) = *(const u16x8*)&tmp[8];
    }
}

// ---------------------------------------------------------------------------
// Fused QKV GEMM: C = xb(8192x512) * Wt^T(512x1536), BM=BN=128, BK=64, 4 waves.
// 1-D grid, XCD-chunked. nt 0-3 -> Q (scaled), 4-7 -> K, 8-11 -> V^T.
// ---------------------------------------------------------------------------
__global__ __launch_bounds__(256) void gemm_kernel(
    const u16* __restrict__ xb, const u16* __restrict__ Wt,
    u16* __restrict__ Qb, u16* __restrict__ Kb, u16* __restrict__ Vb)
{
    const int bid = blockIdx.x;
    const int xcd = bid & 7;
    const int j   = bid >> 3;            // 0..95
    const int mt  = xcd * 8 + (j / 12);  // 0..63
    const int nt  = j % 12;
    const int m0 = mt * 128;
    const int n0 = nt * 128;
    const int tid = threadIdx.x;
    const int w = tid >> 6, l = tid & 63, lr = l & 15, lh = l >> 4;
    const int wr = w >> 1, wc = w & 1;

    __shared__ u16 smem[16896];     // A:[0,8192) B:[8192,16384); V-retile 128*132
    u16* As = smem;
    u16* Bs = smem + 8192;

    f32x4 acc[4][4];
    const f32x4 fzero = {0.f, 0.f, 0.f, 0.f};
    #pragma unroll
    for (int mi = 0; mi < 4; ++mi)
        #pragma unroll
        for (int nj = 0; nj < 4; ++nj) acc[mi][nj] = fzero;

    for (int kt = 0; kt < 8; ++kt) {
        const int k0 = kt * 64;
        #pragma unroll
        for (int i = 0; i < 4; ++i) {
            const int cid = i * 256 + tid;
            const int row = cid >> 3, ch = cid & 7;
            const int sch = ch ^ (row & 7);
            u16* dstA = As + (i * 256 + w * 64) * 8;   // wave-uniform base
            u16* dstB = Bs + (i * 256 + w * 64) * 8;
            gload16(xb + (size_t)(m0 + row) * DMODEL + k0 + sch * 8, dstA);
            gload16(Wt + (size_t)(n0 + row) * DMODEL + k0 + sch * 8, dstB);
        }
        __syncthreads();

        #pragma unroll
        for (int kk = 0; kk < 2; ++kk) {
            const int cs = (kk * 4 + lh) ^ (lr & 7);   // swizzled chunk
            bf16x8 af[4], bfr[4];
            #pragma unroll
            for (int mi = 0; mi < 4; ++mi)
                af[mi] = *(const bf16x8*)(As + (wr * 64 + mi * 16 + lr) * 64 + cs * 8);
            #pragma unroll
            for (int nj = 0; nj < 4; ++nj)
                bfr[nj] = *(const bf16x8*)(Bs + (wc * 64 + nj * 16 + lr) * 64 + cs * 8);
            #pragma unroll
            for (int mi = 0; mi < 4; ++mi)
                #pragma unroll
                for (int nj = 0; nj < 4; ++nj)
                    acc[mi][nj] = __builtin_amdgcn_mfma_f32_16x16x32_bf16(af[mi], bfr[nj], acc[mi][nj], 0, 0, 0);
        }
        __syncthreads();
    }

    const int mat = nt >> 2;
    const int hp  = nt & 3;
    if (mat < 2) {
        u16* Ob = (mat == 0) ? Qb : Kb;
        const float osc = (mat == 0) ? QSCALE : 1.0f;
        #pragma unroll
        for (int mi = 0; mi < 4; ++mi) {
            const int gmb = m0 + wr * 64 + mi * 16 + lh * 4;
            const int b = gmb >> 12;
            #pragma unroll
            for (int rr = 0; rr < 4; ++rr) {
                const int t = (gmb + rr) & 4095;
                const int n = t >> 2, r = t & 3;
                #pragma unroll
                for (int nj = 0; nj < 4; ++nj) {
                    const int c  = wc * 64 + nj * 16 + lr;
                    const int h  = hp * 2 + (c >> 6);
                    const int dk = c & 63;
                    const size_t g = ((size_t)(b * NH + h)) * 4 + r;
                    Ob[(g * NPAD + n) * DHEAD + dk] = f2bf(acc[mi][nj][rr] * osc);
                }
            }
        }
    } else {
        // V: retile via LDS -> coalesced stores of V^T [g][dv][n]
        #pragma unroll
        for (int mi = 0; mi < 4; ++mi) {
            const int nrel = wr * 16 + mi * 4 + lh;
            #pragma unroll
            for (int nj = 0; nj < 4; ++nj) {
                const int c = wc * 64 + nj * 16 + lr;
                #pragma unroll
                for (int rr = 0; rr < 4; ++rr)
                    smem[c * 132 + rr * 32 + nrel] = f2bf(acc[mi][nj][rr]);
            }
        }
        __syncthreads();
        const int b  = m0 >> 12;
        const int nb = (m0 & 4095) >> 2;
        #pragma unroll
        for (int e = 0; e < 2; ++e) {
            const int chunk = e * 256 + tid;
            const int c = chunk & 127, r = chunk >> 7;
            const int h  = hp * 2 + (c >> 6);
            const int dv = c & 63;
            const size_t g = ((size_t)(b * NH + h)) * 4 + r;
            u16* dst = Vb + (g * DHEAD + dv) * NPAD + nb;
            const u16* src = smem + c * 132 + r * 32;
            alignas(16) u16 tmp[32];
            #pragma unroll
            for (int q8 = 0; q8 < 8; ++q8)
                *(u16x4*)&tmp[q8 * 4] = *(const u16x4*)(src + q8 * 4);
            #pragma unroll
            for (int q16 = 0; q16 < 4; ++q16)
                *(u16x8*)(dst + q16 * 8) = *(const u16x8*)&tmp[q16 * 8];
        }
    }
}

// ---------------------------------------------------------------------------
// Flash attention per (b,h,r): 128 queries/block (8 waves x 16 rows),
// 16 key tiles of 64. TRIPLE-buffered K/V, ONE barrier/tile, prefetch issued
// after the barrier (WAR-safe: barrier t separates reads of buf (t-1)%3 from
// the write of tile t+2 into the same buffer).
// ---------------------------------------------------------------------------
__global__ __launch_bounds__(512) void attn_kernel(
    const u16* __restrict__ Qb, const u16* __restrict__ Kb, const u16* __restrict__ Vb,
    float* __restrict__ out)
{
    const int g  = blockIdx.x;          // ((b*8+h)*4+r): blocks sharing g -> same XCD
    const int b  = g >> 5;
    const int h  = (g >> 2) & 7;
    const int r  = g & 3;
    const int q0 = blockIdx.y * 128;
    const int tid = threadIdx.x;
    const int w  = tid >> 6;            // 0..7
    const int l  = tid & 63;
    const int lr = l & 15, lh = l >> 4;

    const u16* Qg  = Qb + (size_t)g * NPAD * DHEAD;
    const u16* Kg  = Kb + (size_t)g * NPAD * DHEAD;
    const u16* Vtg = Vb + (size_t)g * DHEAD * NPAD;   // [dv][n]

    __shared__ u16 KV[3][2][4096];   // [buf][K/V][64 rows][8 slots][8 u16]
    __shared__ u16 Ps[8][16][68];    // per-wave P tile [qrow][m]

    // staging: thread -> (row = tid>>3, slot = tid&7), source chunk XOR-swizzled
    const int srow = tid >> 3;
    const int ssch = (tid & 7) ^ (srow & 7);
    const u16* ksrc0 = Kg  + (size_t)srow * DHEAD + ssch * 8;
    const u16* vsrc0 = Vtg + (size_t)srow * NPAD  + ssch * 8;

    bf16x8 qa[2];
    {
        const u16* qrow = Qg + (size_t)(q0 + w * 16 + lr) * DHEAD;
        qa[0] = *(const bf16x8*)(qrow + lh * 8);
        qa[1] = *(const bf16x8*)(qrow + 32 + lh * 8);
    }

    const f32x4 fzero = {0.f, 0.f, 0.f, 0.f};
    f32x4 o[4];
    #pragma unroll
    for (int j = 0; j < 4; ++j) o[j] = fzero;
    float Lpart[4] = {0.f, 0.f, 0.f, 0.f};

    const int qw0 = q0 + w * 16;

    // prologue: stage tiles 0,1 into bufs 0,1
    gload16(ksrc0,              &KV[0][0][w * 512]);
    gload16(vsrc0,              &KV[0][1][w * 512]);
    gload16(ksrc0 + 64 * DHEAD, &KV[1][0][w * 512]);
    gload16(vsrc0 + 64,         &KV[1][1][w * 512]);

    for (int mt = 0; mt < 16; ++mt) {
        if (mt < 15) asm volatile("s_waitcnt vmcnt(2)" ::: "memory");
        else         asm volatile("s_waitcnt vmcnt(0)" ::: "memory");
        __builtin_amdgcn_s_barrier();
        // issue tile mt+2 AFTER the barrier (WAR-safe vs readers of tile mt-1)
        if (mt < 14) {
            const int nb = (mt + 2) % 3;
            gload16(ksrc0 + (size_t)(mt + 2) * 64 * DHEAD, &KV[nb][0][w * 512]);
            gload16(vsrc0 + (mt + 2) * 64,                 &KV[nb][1][w * 512]);
        }

        const u16* Kbuf = KV[mt % 3][0];
        const u16* Vbuf = KV[mt % 3][1];

        // S = Q K^T (wave: 16 x 64), logits already in log2 space
        f32x4 s[4];
        __builtin_amdgcn_s_setprio(1);
        #pragma unroll
        for (int ni = 0; ni < 4; ++ni) {
            const int rbase = (ni * 16 + lr) * 8;
            const int sl0 = lh ^ (lr & 7), sl1 = (4 + lh) ^ (lr & 7);
            bf16x8 kb0 = *(const bf16x8*)(Kbuf + (rbase + sl0) * 8);
            bf16x8 kb1 = *(const bf16x8*)(Kbuf + (rbase + sl1) * 8);
            f32x4 t = __builtin_amdgcn_mfma_f32_16x16x32_bf16(qa[0], kb0, fzero, 0, 0, 0);
            s[ni] = __builtin_amdgcn_mfma_f32_16x16x32_bf16(qa[1], kb1, t, 0, 0, 0);
        }
        __builtin_amdgcn_s_setprio(0);

        const int m0 = mt * 64;
        const bool special = (m0 + 66 >= qw0) && (m0 <= qw0 + 18);
        if (!special) {
            #pragma unroll
            for (int ni = 0; ni < 4; ++ni) {
                #pragma unroll
                for (int rr = 0; rr < 4; ++rr) {
                    const float p = __builtin_amdgcn_exp2f(s[ni][rr]);
                    Lpart[rr] += p;
                    Ps[w][lh * 4 + rr][ni * 16 + lr] = cvt_bf(p);
                }
            }
        } else {
            #pragma unroll
            for (int ni = 0; ni < 4; ++ni) {
                const int mg = m0 + ni * 16 + lr;
                #pragma unroll
                for (int rr = 0; rr < 4; ++rr) {
                    const int qg = qw0 + lh * 4 + rr;
                    float v = s[ni][rr];
                    const int dd = mg - qg;
                    if (dd >= -3 && dd <= 3) v += 1.0f;    // window doubling
                    const float p = __builtin_amdgcn_exp2f(v);
                    Lpart[rr] += p;
                    Ps[w][lh * 4 + rr][ni * 16 + lr] = cvt_bf(p);
                }
            }
        }

        // O += P V (Ps per-wave: intra-wave lgkmcnt ordering only)
        __builtin_amdgcn_s_setprio(1);
        #pragma unroll
        for (int kk = 0; kk < 2; ++kk) {
            const int slot = (kk * 4 + lh) ^ (lr & 7);
            bf16x8 pa = *(const bf16x8*)&Ps[w][lr][kk * 32 + lh * 8];
            #pragma unroll
            for (int j = 0; j < 4; ++j) {
                bf16x8 vb = *(const bf16x8*)(Vbuf + ((j * 16 + lr) * 8 + slot) * 8);
                o[j] = __builtin_amdgcn_mfma_f32_16x16x32_bf16(pa, vb, o[j], 0, 0, 0);
            }
        }
        __builtin_amdgcn_s_setprio(0);
        // no trailing barrier: next iteration's barrier covers the WAR hazard
    }

    // epilogue: dense zero-key (+1), its window double (q>=1021 ? +1), OOB (+coob)
    #pragma unroll
    for (int rr = 0; rr < 4; ++rr) {
        float s_ = Lpart[rr];
        #pragma unroll
        for (int off = 1; off < 16; off <<= 1)
            s_ += __shfl_xor(s_, off, 16);
        const int qg = qw0 + lh * 4 + rr;
        const int coob = (qg < 3 ? 3 - qg : 0) + (qg > 1021 ? qg - 1021 : 0);
        const float extra = (float)(coob + 1 + (qg >= 1021 ? 1 : 0));
        const float inv = 1.0f / (s_ + extra);
        const int t = qg * 4 + r;
        float* orow = out + ((size_t)b * LSEQ + t) * DMODEL + h * DHEAD;
        #pragma unroll
        for (int j = 0; j < 4; ++j)
            orow[j * 16 + lr] = o[j][rr] * inv;
    }
}

extern "C" void kernel_launch(void* const* d_in, const int* in_sizes, int n_in,
                              void* d_out, int out_size, void* d_ws, size_t ws_size,
                              hipStream_t stream) {
    const float* x  = (const float*)d_in[0];
    const float* Wq = (const float*)d_in[1];
    const float* Wk = (const float*)d_in[2];
    const float* Wv = (const float*)d_in[3];
    float* out = (float*)d_out;

    const size_t SZ = (size_t)BATCH * NH * 4 * NPAD * DHEAD;   // per-tensor elems
    u16* Qb = (u16*)d_ws;
    u16* Kb = Qb + SZ;
    u16* Vb = Kb + SZ;

    // scratch for bf16 x and transposed W lives in d_out (overwritten by attn)
    u16* xb = (u16*)d_out;                       // 8192*512 u16
    u16* Wt = xb + (size_t)8192 * 512;           // 1536*512 u16

    prep_kernel<<<2240, 256, 0, stream>>>(x, Wq, Wk, Wv, xb, Wt);

    gemm_kernel<<<768, 256, 0, stream>>>(xb, Wt, Qb, Kb, Vb);

    dim3 ga(64, 8);
    attn_kernel<<<ga, 512, 0, stream>>>(Qb, Kb, Vb, out);
}